// Round 14
// baseline (164.822 us; speedup 1.0000x reference)
//
#include <hip/hip_runtime.h>

typedef unsigned short u16;
typedef unsigned int u32;
typedef short v8s __attribute__((ext_vector_type(8)));
typedef float v16f __attribute__((ext_vector_type(16)));
typedef unsigned int v2u __attribute__((ext_vector_type(2)));

#define MFMA(a, b, c) __builtin_amdgcn_mfma_f32_32x32x16_bf16(a, b, c, 0, 0, 0)
#define L2E 1.44269504088896f

union U8 { v8s s; uint4 u4; u32 u[4]; };

__device__ __forceinline__ u16 f2bf(float x) {            // round-nearest-even
    u32 u = __float_as_uint(x);
    return (u16)((u + 0x7FFFu + ((u >> 16) & 1u)) >> 16);
}
__device__ __forceinline__ u32 pk2(float a, float b) {
    return (u32)f2bf(a) | ((u32)f2bf(b) << 16);
}
// RTZ bf16x2 pack in ONE instruction
__device__ __forceinline__ u32 pkz(float e0, float e1) {
    return __builtin_amdgcn_perm(__float_as_uint(e1), __float_as_uint(e0), 0x07060302u);
}

// ======== frag-tiled layouts (u16 units), identical to R8-R10 ========
// qfT/kfT: [b][t32][f][lane][j]   t32 = (q|key)>>5   (4*128*2*512)
// vfT:     [b][ct][tk][lane][j]   ct = ch>>5, tk = key>>4 (4*8*256*512)
// WfT:     [cht][kc][lane][j]     cht = ch>>5 (10)       (160*512)

// ---- prep_w ----
__global__ __launch_bounds__(256) void prep_w_kernel(
    const float* __restrict__ Wq, const float* __restrict__ bq,
    const float* __restrict__ Wk, const float* __restrict__ bk,
    const float* __restrict__ Wv, const float* __restrict__ bv,
    u16* __restrict__ WfT, float* __restrict__ ball)
{
    int tid = blockIdx.x * 256 + threadIdx.x;
    if (tid < 81920) {
        int ch = tid >> 8, c = tid & 255;
        float w;
        if (ch < 32)      w = Wq[ch * 256 + c];
        else if (ch < 64) w = Wk[(ch - 32) * 256 + c] * L2E;
        else              w = Wv[(ch - 64) * 256 + c];
        int tile = (ch >> 5) * 16 + (c >> 4);
        int lane = ((c >> 3) & 1) * 32 + (ch & 31);
        WfT[tile * 512 + lane * 8 + (c & 7)] = f2bf(w);
    } else if (tid < 82240) {
        int i = tid - 81920;
        float bb;
        if (i < 32)      bb = bq[i];
        else if (i < 64) bb = bk[i - 32] * L2E;
        else             bb = bv[i - 64];
        ball[i] = bb;
    }
}

// ---- proj (R10, unchanged): grid 512, 4 waves, 2 blocks/CU ----
__global__ __launch_bounds__(256, 2) void proj_kernel(
    const float* __restrict__ xc, const float* __restrict__ xd,
    const u16* __restrict__ WfT, const float* __restrict__ ball,
    u16* __restrict__ qfT, u16* __restrict__ kfT, u16* __restrict__ vfT)
{
    __shared__ u16 xls[2][32][264];   // [arr][n][c] bf16, 33.8 KB
    int blk = blockIdx.x, b = blk >> 7, n0 = (blk & 127) * 32;
    int t = threadIdx.x, lane = t & 63, wv = t >> 6;
    int hl = lane >> 5, l31 = lane & 31;

#pragma unroll
    for (int p = 0; p < 4; p++) {
        int s = p * 256 + t;
        int arr = s >> 9, c4 = (s >> 3) & 63, n4s = s & 7;
        const float* src = arr ? xd : xc;
        size_t g0 = ((size_t)(b * 256 + c4 * 4)) * 4096 + n0 + n4s * 4;
        float4 r0 = *(const float4*)&src[g0];
        float4 r1 = *(const float4*)&src[g0 + 4096];
        float4 r2 = *(const float4*)&src[g0 + 8192];
        float4 r3 = *(const float4*)&src[g0 + 12288];
        *(uint2*)&xls[arr][n4s * 4 + 0][c4 * 4] = make_uint2(pk2(r0.x, r1.x), pk2(r2.x, r3.x));
        *(uint2*)&xls[arr][n4s * 4 + 1][c4 * 4] = make_uint2(pk2(r0.y, r1.y), pk2(r2.y, r3.y));
        *(uint2*)&xls[arr][n4s * 4 + 2][c4 * 4] = make_uint2(pk2(r0.z, r1.z), pk2(r2.z, r3.z));
        *(uint2*)&xls[arr][n4s * 4 + 3][c4 * 4] = make_uint2(pk2(r0.w, r1.w), pk2(r2.w, r3.w));
    }
    __syncthreads();

    int jobs[3];
    int nj;
    if (wv == 0)      { jobs[0] = 0; jobs[1] = 2; jobs[2] = 0; nj = 2; }
    else if (wv == 1) { jobs[0] = 1; jobs[1] = 3; jobs[2] = 0; nj = 2; }
    else if (wv == 2) { jobs[0] = 4; jobs[1] = 5; jobs[2] = 6; nj = 3; }
    else              { jobs[0] = 7; jobs[1] = 8; jobs[2] = 9; nj = 3; }

    int nt = blk & 127;
    int n = n0 + l31;
    int vl = ((n >> 3) & 1) * 32, tk = n >> 4, j8 = n & 7;

    for (int jj = 0; jj < nj; jj++) {
        int j = jobs[jj];
        int arr = (j != 0);
        const u16* wb = WfT + (size_t)(j * 16) * 512 + lane * 8;
        v16f acc = {};
#pragma unroll
        for (int kc = 0; kc < 16; kc++) {
            U8 bx, a;
            bx.u4 = *(const uint4*)&xls[arr][l31][kc * 16 + hl * 8];
            a.u4  = *(const uint4*)(wb + (size_t)kc * 512);
            acc = MFMA(a.s, bx.s, acc);
        }
        if (j <= 1) {
            u16* dst = j ? kfT : qfT;
#pragma unroll
            for (int i = 0; i < 8; i++) {
                int r = 2 * i;
                int row = (r & 3) + 8 * (r >> 2) + 4 * hl;
                float b0 = ball[j * 32 + row], b1 = ball[j * 32 + row + 1];
                u32 st = pk2(acc[r] + b0, acc[r + 1] + b1);
                size_t off = (((size_t)(b * 128 + nt) * 2 + (row >> 4)) * 512)
                           + (((row >> 3) & 1) * 32 + l31) * 8 + (row & 7);
                *(u32*)&dst[off] = st;
            }
        } else {
            int vi = j - 2;
            u16* vdst = vfT + (((size_t)(b * 8 + vi) * 256 + tk) * 512) + vl * 8 + j8;
#pragma unroll
            for (int r = 0; r < 16; r++) {
                int row = (r & 3) + 8 * (r >> 2) + 4 * hl;
                vdst[row * 8] = f2bf(acc[r] + ball[64 + vi * 32 + row]);
            }
        }
    }
}

// ---- flash R17: R16 + own-tile-in-registers.                            ----
// With the chq rotation, each wave's FIRST consumed tile (j=0) is the one ----
// it produced (slot wv). Keep the produced B0/B1 in registers across the  ----
// barrier and skip that LDS read: 8 -> 6 ds_read_b128 per wave/superstep. ----
// LDS writes unchanged (3 other waves still read the tile).               ----
union ShU {
    u32   P[2][8][520];           // [buf][tile][h*256+lane*4+i], pad->+8 banks/tile, 33.3 KB
    float red[4][2][16][64];      // epilogue kq-reduce (aliases P) 32 KB
};

__global__ __launch_bounds__(512, 4) void flash_kernel(
    const u16* __restrict__ qfT, const u16* __restrict__ kfT,
    const u16* __restrict__ vfT, const float* __restrict__ xccd,
    const float* __restrict__ gptr, float* __restrict__ outp)
{
    __shared__ ShU sh;
    __shared__ float lred[8][32];

    const int t = threadIdx.x, lane = t & 63, wv = t >> 6;
    const int hl = lane >> 5, l31 = lane & 31;
    const int blk = blockIdx.x;
    const int b  = (blk & 7) >> 1;                      // XCD-pair pinning
    const int qt = ((blk >> 3) << 1) | (blk & 1);       // 0..127
    const int kq = wv >> 2, chq = wv & 3;
    const int n0 = qt * 32;

    U8 qf0, qf1;
    {
        const u16* qp = qfT + ((size_t)(b * 128 + qt) * 2) * 512 + lane * 8;
        qf0.u4 = *(const uint4*)qp;
        qf1.u4 = *(const uint4*)(qp + 512);
    }

    v16f acc[2] = {};
    float lrun = 0.f;
    U8 rB0, rB1;                    // own tile's P fragments, reg-resident

    // producer K: tile(s) = s*8 + wv ; per-superstep stride 8192 u16
    const u16* kp = kfT + ((size_t)(b * 128 + wv)) * 1024 + lane * 8;
    // consumer V: ct = chq*2 + ctl ; ctl stride = 256*512 = 131072 u16
    const u16* vp = vfT + ((size_t)(b * 8 + chq * 2) * 256) * 512 + lane * 8;

    U8 kb0[2], kb1[2];
    kb0[0].u4 = *(const uint4*)(kp);
    kb0[1].u4 = *(const uint4*)(kp + 512);
    kb1[0].u4 = *(const uint4*)(kp + 8192);
    kb1[1].u4 = *(const uint4*)(kp + 8192 + 512);

    auto produce = [&](U8 (&kb)[2], int buf) {
        v16f E = {};
        E = MFMA(kb[0].s, qf0.s, E);
        E = MFMA(kb[1].s, qf1.s, E);
        u32 pkv[8];
#pragma unroll
        for (int j = 0; j < 8; j++)
            pkv[j] = pkz(__builtin_amdgcn_exp2f(E[2 * j]),
                         __builtin_amdgcn_exp2f(E[2 * j + 1]));
        float sl = 0.f;   // l partial: sum of bf16-ROUNDED P (matches PV numerator)
#pragma unroll
        for (int j = 0; j < 8; j++) {
            sl += __uint_as_float(pkv[j] & 0xFFFF0000u);
            sl += __uint_as_float(pkv[j] << 16);
        }
        lrun += sl;
        U8 B0, B1;
        v2u r;
        r = __builtin_amdgcn_permlane32_swap(pkv[0], pkv[2], 0, 0); B0.u[0] = r[0]; B0.u[2] = r[1];
        r = __builtin_amdgcn_permlane32_swap(pkv[1], pkv[3], 0, 0); B0.u[1] = r[0]; B0.u[3] = r[1];
        r = __builtin_amdgcn_permlane32_swap(pkv[4], pkv[6], 0, 0); B1.u[0] = r[0]; B1.u[2] = r[1];
        r = __builtin_amdgcn_permlane32_swap(pkv[5], pkv[7], 0, 0); B1.u[1] = r[0]; B1.u[3] = r[1];
        *(uint4*)&sh.P[buf][wv][lane * 4]       = B0.u4;
        *(uint4*)&sh.P[buf][wv][256 + lane * 4] = B1.u4;
        rB0 = B0; rB1 = B1;         // keep own tile in regs for j=0 consumption
    };

    produce(kb0, 0);          // P for superstep 0
    __syncthreads();

    const int tb = kq * 4;    // this wave's 4 tile slots; consumed in chq-rotated order
#pragma unroll 1
    for (int s = 0; s < 16; s++) {
        const int cb = s & 1, nb = cb ^ 1;
        // j=0 tile is OWN tile (tb + chq == wv): take from registers, no LDS read
        const int T0  = s * 8 + wv;
        U8 bA0, bA1, bB0, bB1;
        bA0 = rB0;
        bA1 = rB1;
        U8 vA[2][2], vB[2][2];
        {
            const u16* v0p = vp + (size_t)(2 * T0) * 512;
            vA[0][0].u4 = *(const uint4*)(v0p);
            vA[0][1].u4 = *(const uint4*)(v0p + 512);
            vA[1][0].u4 = *(const uint4*)(v0p + 131072);
            vA[1][1].u4 = *(const uint4*)(v0p + 131072 + 512);
        }
        // produce next superstep's P (overwrites rB0/rB1 AFTER j=0 copy); prefetch K(s+2)
        if (s < 15) {
            if ((s & 1) == 0) {
                produce(kb1, nb);
                if (s < 14) {
                    kb0[0].u4 = *(const uint4*)(kp + (size_t)(s + 2) * 8192);
                    kb0[1].u4 = *(const uint4*)(kp + (size_t)(s + 2) * 8192 + 512);
                }
            } else {
                produce(kb0, nb);
                if (s < 14) {
                    kb1[0].u4 = *(const uint4*)(kp + (size_t)(s + 2) * 8192);
                    kb1[1].u4 = *(const uint4*)(kp + (size_t)(s + 2) * 8192 + 512);
                }
            }
        }
        // PV over 4 rotated tile slots, B/V double-buffered (j>=1 tiles from LDS)
#pragma unroll
        for (int j = 0; j < 4; j++) {
            if (j < 3) {
                const int tln = tb + ((chq + j + 1) & 3);
                const int Tn  = s * 8 + tln;
                bB0.u4 = *(const uint4*)&sh.P[cb][tln][lane * 4];
                bB1.u4 = *(const uint4*)&sh.P[cb][tln][256 + lane * 4];
                const u16* vnp = vp + (size_t)(2 * Tn) * 512;
                vB[0][0].u4 = *(const uint4*)(vnp);
                vB[0][1].u4 = *(const uint4*)(vnp + 512);
                vB[1][0].u4 = *(const uint4*)(vnp + 131072);
                vB[1][1].u4 = *(const uint4*)(vnp + 131072 + 512);
            }
            __builtin_amdgcn_s_setprio(1);
            acc[0] = MFMA(vA[0][0].s, bA0.s, acc[0]);
            acc[0] = MFMA(vA[0][1].s, bA1.s, acc[0]);
            acc[1] = MFMA(vA[1][0].s, bA0.s, acc[1]);
            acc[1] = MFMA(vA[1][1].s, bA1.s, acc[1]);
            __builtin_amdgcn_s_setprio(0);
            bA0 = bB0; bA1 = bB1;
            vA[0][0] = vB[0][0]; vA[0][1] = vB[0][1];
            vA[1][0] = vB[1][0]; vA[1][1] = vB[1][1];
        }
        __syncthreads();
    }

    // ---- epilogue: l finalize, kq-reduce, scale, residual ----
    {
        v2u rr = __builtin_amdgcn_permlane32_swap(__float_as_uint(lrun),
                                                  __float_as_uint(lrun), 0, 0);
        float ltot = __uint_as_float(rr[0]) + __uint_as_float(rr[1]);
        if (lane < 32) lred[wv][l31] = ltot;
    }
    if (kq == 1) {
#pragma unroll
        for (int ct = 0; ct < 2; ct++)
#pragma unroll
            for (int r = 0; r < 16; r++)
                sh.red[chq][ct][r][lane] = acc[ct][r];
    }
    __syncthreads();
    if (kq == 0) {
        float lsum = 0.f;
#pragma unroll
        for (int w = 0; w < 8; w++) lsum += lred[w][l31];
        const float g = gptr[0];
        const float sc = g / lsum;
#pragma unroll
        for (int ct = 0; ct < 2; ct++)
#pragma unroll
            for (int r = 0; r < 16; r++) {
                float v = acc[ct][r] + sh.red[chq][ct][r][lane];
                int ch = chq * 64 + ct * 32 + (r & 3) + 8 * (r >> 2) + 4 * hl;
                size_t ga = ((size_t)(b * 256 + ch)) * 4096 + n0 + l31;
                outp[ga] = v * sc + xccd[ga];
            }
    }
}

extern "C" void kernel_launch(void* const* d_in, const int* in_sizes, int n_in,
                              void* d_out, int out_size, void* d_ws, size_t ws_size,
                              hipStream_t stream)
{
    const float* xc    = (const float*)d_in[0];
    const float* xd    = (const float*)d_in[1];
    const float* Wq    = (const float*)d_in[2];
    const float* bq    = (const float*)d_in[3];
    const float* Wk    = (const float*)d_in[4];
    const float* bk    = (const float*)d_in[5];
    const float* Wv    = (const float*)d_in[6];
    const float* bv    = (const float*)d_in[7];
    const float* gamma = (const float*)d_in[8];
    float* out = (float*)d_out;

    // ws (u16): qfT 512K | kfT 512K | vfT 4M | WfT 80K | ball
    u16* qfT  = (u16*)d_ws;
    u16* kfT  = qfT + (size_t)524288;
    u16* vfT  = kfT + (size_t)524288;
    u16* WfT  = vfT + (size_t)4194304;
    float* bl = (float*)(WfT + 81920);

    prep_w_kernel<<<322, 256, 0, stream>>>(Wq, bq, Wk, bk, Wv, bv, WfT, bl);
    proj_kernel<<<512, 256, 0, stream>>>(xc, xd, WfT, bl, qfT, kfT, vfT);
    flash_kernel<<<512, 512, 0, stream>>>(qfT, kfT, vfT, xc, gamma, out);
}

// Round 18
// 154.637 us; speedup vs baseline: 1.0659x; 1.0659x over previous
//
#include <hip/hip_runtime.h>

typedef unsigned short u16;
typedef unsigned int u32;
typedef short v8s __attribute__((ext_vector_type(8)));
typedef float v16f __attribute__((ext_vector_type(16)));
typedef unsigned int v2u __attribute__((ext_vector_type(2)));

#define MFMA(a, b, c) __builtin_amdgcn_mfma_f32_32x32x16_bf16(a, b, c, 0, 0, 0)
#define L2E 1.44269504088896f

union U8 { v8s s; uint4 u4; u32 u[4]; };

__device__ __forceinline__ u16 f2bf(float x) {            // round-nearest-even
    u32 u = __float_as_uint(x);
    return (u16)((u + 0x7FFFu + ((u >> 16) & 1u)) >> 16);
}
__device__ __forceinline__ u32 pk2(float a, float b) {
    return (u32)f2bf(a) | ((u32)f2bf(b) << 16);
}
// RTZ bf16x2 pack in ONE instruction
__device__ __forceinline__ u32 pkz(float e0, float e1) {
    return __builtin_amdgcn_perm(__float_as_uint(e1), __float_as_uint(e0), 0x07060302u);
}

// ======== frag-tiled layouts (u16 units), identical to R8-R10 ========
// qfT/kfT: [b][t32][f][lane][j]   t32 = (q|key)>>5   (4*128*2*512)
// vfT:     [b][ct][tk][lane][j]   ct = ch>>5, tk = key>>4 (4*8*256*512)
// WfT:     [cht][kc][lane][j]     cht = ch>>5 (10)       (160*512)

// ---- prep_w ----
__global__ __launch_bounds__(256) void prep_w_kernel(
    const float* __restrict__ Wq, const float* __restrict__ bq,
    const float* __restrict__ Wk, const float* __restrict__ bk,
    const float* __restrict__ Wv, const float* __restrict__ bv,
    u16* __restrict__ WfT, float* __restrict__ ball)
{
    int tid = blockIdx.x * 256 + threadIdx.x;
    if (tid < 81920) {
        int ch = tid >> 8, c = tid & 255;
        float w;
        if (ch < 32)      w = Wq[ch * 256 + c];
        else if (ch < 64) w = Wk[(ch - 32) * 256 + c] * L2E;
        else              w = Wv[(ch - 64) * 256 + c];
        int tile = (ch >> 5) * 16 + (c >> 4);
        int lane = ((c >> 3) & 1) * 32 + (ch & 31);
        WfT[tile * 512 + lane * 8 + (c & 7)] = f2bf(w);
    } else if (tid < 82240) {
        int i = tid - 81920;
        float bb;
        if (i < 32)      bb = bq[i];
        else if (i < 64) bb = bk[i - 32] * L2E;
        else             bb = bv[i - 64];
        ball[i] = bb;
    }
}

// ---- proj (R10, unchanged): grid 512, 4 waves, 2 blocks/CU ----
__global__ __launch_bounds__(256, 2) void proj_kernel(
    const float* __restrict__ xc, const float* __restrict__ xd,
    const u16* __restrict__ WfT, const float* __restrict__ ball,
    u16* __restrict__ qfT, u16* __restrict__ kfT, u16* __restrict__ vfT)
{
    __shared__ u16 xls[2][32][264];   // [arr][n][c] bf16, 33.8 KB
    int blk = blockIdx.x, b = blk >> 7, n0 = (blk & 127) * 32;
    int t = threadIdx.x, lane = t & 63, wv = t >> 6;
    int hl = lane >> 5, l31 = lane & 31;

#pragma unroll
    for (int p = 0; p < 4; p++) {
        int s = p * 256 + t;
        int arr = s >> 9, c4 = (s >> 3) & 63, n4s = s & 7;
        const float* src = arr ? xd : xc;
        size_t g0 = ((size_t)(b * 256 + c4 * 4)) * 4096 + n0 + n4s * 4;
        float4 r0 = *(const float4*)&src[g0];
        float4 r1 = *(const float4*)&src[g0 + 4096];
        float4 r2 = *(const float4*)&src[g0 + 8192];
        float4 r3 = *(const float4*)&src[g0 + 12288];
        *(uint2*)&xls[arr][n4s * 4 + 0][c4 * 4] = make_uint2(pk2(r0.x, r1.x), pk2(r2.x, r3.x));
        *(uint2*)&xls[arr][n4s * 4 + 1][c4 * 4] = make_uint2(pk2(r0.y, r1.y), pk2(r2.y, r3.y));
        *(uint2*)&xls[arr][n4s * 4 + 2][c4 * 4] = make_uint2(pk2(r0.z, r1.z), pk2(r2.z, r3.z));
        *(uint2*)&xls[arr][n4s * 4 + 3][c4 * 4] = make_uint2(pk2(r0.w, r1.w), pk2(r2.w, r3.w));
    }
    __syncthreads();

    int jobs[3];
    int nj;
    if (wv == 0)      { jobs[0] = 0; jobs[1] = 2; jobs[2] = 0; nj = 2; }
    else if (wv == 1) { jobs[0] = 1; jobs[1] = 3; jobs[2] = 0; nj = 2; }
    else if (wv == 2) { jobs[0] = 4; jobs[1] = 5; jobs[2] = 6; nj = 3; }
    else              { jobs[0] = 7; jobs[1] = 8; jobs[2] = 9; nj = 3; }

    int nt = blk & 127;
    int n = n0 + l31;
    int vl = ((n >> 3) & 1) * 32, tk = n >> 4, j8 = n & 7;

    for (int jj = 0; jj < nj; jj++) {
        int j = jobs[jj];
        int arr = (j != 0);
        const u16* wb = WfT + (size_t)(j * 16) * 512 + lane * 8;
        v16f acc = {};
#pragma unroll
        for (int kc = 0; kc < 16; kc++) {
            U8 bx, a;
            bx.u4 = *(const uint4*)&xls[arr][l31][kc * 16 + hl * 8];
            a.u4  = *(const uint4*)(wb + (size_t)kc * 512);
            acc = MFMA(a.s, bx.s, acc);
        }
        if (j <= 1) {
            u16* dst = j ? kfT : qfT;
#pragma unroll
            for (int i = 0; i < 8; i++) {
                int r = 2 * i;
                int row = (r & 3) + 8 * (r >> 2) + 4 * hl;
                float b0 = ball[j * 32 + row], b1 = ball[j * 32 + row + 1];
                u32 st = pk2(acc[r] + b0, acc[r + 1] + b1);
                size_t off = (((size_t)(b * 128 + nt) * 2 + (row >> 4)) * 512)
                           + (((row >> 3) & 1) * 32 + l31) * 8 + (row & 7);
                *(u32*)&dst[off] = st;
            }
        } else {
            int vi = j - 2;
            u16* vdst = vfT + (((size_t)(b * 8 + vi) * 256 + tk) * 512) + vl * 8 + j8;
#pragma unroll
            for (int r = 0; r < 16; r++) {
                int row = (r & 3) + 8 * (r >> 2) + 4 * hl;
                vdst[row * 8] = f2bf(acc[r] + ball[64 + vi * 32 + row]);
            }
        }
    }
}

// ---- flash R18: R17 (own-tile-in-reg, 6 LDS reads/wave/ss) with the     ----
// ---- +8-reg cost of rB paid for by DROPPING the K double-buffer:        ----
// ---- single kb, reloaded K(s+2) after produce(s+1) consumes it.         ----
// ---- Net register delta vs non-spilling R16: zero.                      ----
union ShU {
    u32   P[2][8][520];           // [buf][tile][h*256+lane*4+i], pad->+8 banks/tile, 33.3 KB
    float red[4][2][16][64];      // epilogue kq-reduce (aliases P) 32 KB
};

__global__ __launch_bounds__(512, 4) void flash_kernel(
    const u16* __restrict__ qfT, const u16* __restrict__ kfT,
    const u16* __restrict__ vfT, const float* __restrict__ xccd,
    const float* __restrict__ gptr, float* __restrict__ outp)
{
    __shared__ ShU sh;
    __shared__ float lred[8][32];

    const int t = threadIdx.x, lane = t & 63, wv = t >> 6;
    const int hl = lane >> 5, l31 = lane & 31;
    const int blk = blockIdx.x;
    const int b  = (blk & 7) >> 1;                      // XCD-pair pinning
    const int qt = ((blk >> 3) << 1) | (blk & 1);       // 0..127
    const int kq = wv >> 2, chq = wv & 3;
    const int n0 = qt * 32;

    U8 qf0, qf1;
    {
        const u16* qp = qfT + ((size_t)(b * 128 + qt) * 2) * 512 + lane * 8;
        qf0.u4 = *(const uint4*)qp;
        qf1.u4 = *(const uint4*)(qp + 512);
    }

    v16f acc[2] = {};
    float lrun = 0.f;
    U8 rB0, rB1;                    // own tile's P fragments, reg-resident

    // producer K: tile(s) = s*8 + wv ; per-superstep stride 8192 u16
    const u16* kp = kfT + ((size_t)(b * 128 + wv)) * 1024 + lane * 8;
    // consumer V: ct = chq*2 + ctl ; ctl stride = 256*512 = 131072 u16
    const u16* vp = vfT + ((size_t)(b * 8 + chq * 2) * 256) * 512 + lane * 8;

    U8 kb[2];                       // SINGLE K buffer (no double-buffer)
    kb[0].u4 = *(const uint4*)(kp);
    kb[1].u4 = *(const uint4*)(kp + 512);

    auto produce = [&](int buf) {
        v16f E = {};
        E = MFMA(kb[0].s, qf0.s, E);
        E = MFMA(kb[1].s, qf1.s, E);
        u32 pkv[8];
#pragma unroll
        for (int j = 0; j < 8; j++)
            pkv[j] = pkz(__builtin_amdgcn_exp2f(E[2 * j]),
                         __builtin_amdgcn_exp2f(E[2 * j + 1]));
        float sl = 0.f;   // l partial: sum of bf16-ROUNDED P (matches PV numerator)
#pragma unroll
        for (int j = 0; j < 8; j++) {
            sl += __uint_as_float(pkv[j] & 0xFFFF0000u);
            sl += __uint_as_float(pkv[j] << 16);
        }
        lrun += sl;
        U8 B0, B1;
        v2u r;
        r = __builtin_amdgcn_permlane32_swap(pkv[0], pkv[2], 0, 0); B0.u[0] = r[0]; B0.u[2] = r[1];
        r = __builtin_amdgcn_permlane32_swap(pkv[1], pkv[3], 0, 0); B0.u[1] = r[0]; B0.u[3] = r[1];
        r = __builtin_amdgcn_permlane32_swap(pkv[4], pkv[6], 0, 0); B1.u[0] = r[0]; B1.u[2] = r[1];
        r = __builtin_amdgcn_permlane32_swap(pkv[5], pkv[7], 0, 0); B1.u[1] = r[0]; B1.u[3] = r[1];
        *(uint4*)&sh.P[buf][wv][lane * 4]       = B0.u4;
        *(uint4*)&sh.P[buf][wv][256 + lane * 4] = B1.u4;
        rB0 = B0; rB1 = B1;         // keep own tile in regs for j=0 consumption
    };

    produce(0);               // P for superstep 0 (uses kb = K tile 0)
    kb[0].u4 = *(const uint4*)(kp + 8192);        // K tile for superstep 1
    kb[1].u4 = *(const uint4*)(kp + 8192 + 512);
    __syncthreads();

    const int tb = kq * 4;    // this wave's 4 tile slots; consumed in chq-rotated order
#pragma unroll 1
    for (int s = 0; s < 16; s++) {
        const int cb = s & 1, nb = cb ^ 1;
        // j=0 tile is OWN tile (tb + chq == wv): take from registers, no LDS read
        const int T0  = s * 8 + wv;
        U8 bA0, bA1, bB0, bB1;
        bA0 = rB0;
        bA1 = rB1;
        U8 vA[2][2], vB[2][2];
        {
            const u16* v0p = vp + (size_t)(2 * T0) * 512;
            vA[0][0].u4 = *(const uint4*)(v0p);
            vA[0][1].u4 = *(const uint4*)(v0p + 512);
            vA[1][0].u4 = *(const uint4*)(v0p + 131072);
            vA[1][1].u4 = *(const uint4*)(v0p + 131072 + 512);
        }
        // produce next superstep's P (consumes kb); then reload kb = K(s+2)
        if (s < 15) {
            produce(nb);
            if (s < 14) {
                kb[0].u4 = *(const uint4*)(kp + (size_t)(s + 2) * 8192);
                kb[1].u4 = *(const uint4*)(kp + (size_t)(s + 2) * 8192 + 512);
            }
        }
        // PV over 4 rotated tile slots, B/V double-buffered (j>=1 tiles from LDS)
#pragma unroll
        for (int j = 0; j < 4; j++) {
            if (j < 3) {
                const int tln = tb + ((chq + j + 1) & 3);
                const int Tn  = s * 8 + tln;
                bB0.u4 = *(const uint4*)&sh.P[cb][tln][lane * 4];
                bB1.u4 = *(const uint4*)&sh.P[cb][tln][256 + lane * 4];
                const u16* vnp = vp + (size_t)(2 * Tn) * 512;
                vB[0][0].u4 = *(const uint4*)(vnp);
                vB[0][1].u4 = *(const uint4*)(vnp + 512);
                vB[1][0].u4 = *(const uint4*)(vnp + 131072);
                vB[1][1].u4 = *(const uint4*)(vnp + 131072 + 512);
            }
            __builtin_amdgcn_s_setprio(1);
            acc[0] = MFMA(vA[0][0].s, bA0.s, acc[0]);
            acc[0] = MFMA(vA[0][1].s, bA1.s, acc[0]);
            acc[1] = MFMA(vA[1][0].s, bA0.s, acc[1]);
            acc[1] = MFMA(vA[1][1].s, bA1.s, acc[1]);
            __builtin_amdgcn_s_setprio(0);
            bA0 = bB0; bA1 = bB1;
            vA[0][0] = vB[0][0]; vA[0][1] = vB[0][1];
            vA[1][0] = vB[1][0]; vA[1][1] = vB[1][1];
        }
        __syncthreads();
    }

    // ---- epilogue: l finalize, kq-reduce, scale, residual ----
    {
        v2u rr = __builtin_amdgcn_permlane32_swap(__float_as_uint(lrun),
                                                  __float_as_uint(lrun), 0, 0);
        float ltot = __uint_as_float(rr[0]) + __uint_as_float(rr[1]);
        if (lane < 32) lred[wv][l31] = ltot;
    }
    if (kq == 1) {
#pragma unroll
        for (int ct = 0; ct < 2; ct++)
#pragma unroll
            for (int r = 0; r < 16; r++)
                sh.red[chq][ct][r][lane] = acc[ct][r];
    }
    __syncthreads();
    if (kq == 0) {
        float lsum = 0.f;
#pragma unroll
        for (int w = 0; w < 8; w++) lsum += lred[w][l31];
        const float g = gptr[0];
        const float sc = g / lsum;
#pragma unroll
        for (int ct = 0; ct < 2; ct++)
#pragma unroll
            for (int r = 0; r < 16; r++) {
                float v = acc[ct][r] + sh.red[chq][ct][r][lane];
                int ch = chq * 64 + ct * 32 + (r & 3) + 8 * (r >> 2) + 4 * hl;
                size_t ga = ((size_t)(b * 256 + ch)) * 4096 + n0 + l31;
                outp[ga] = v * sc + xccd[ga];
            }
    }
}

extern "C" void kernel_launch(void* const* d_in, const int* in_sizes, int n_in,
                              void* d_out, int out_size, void* d_ws, size_t ws_size,
                              hipStream_t stream)
{
    const float* xc    = (const float*)d_in[0];
    const float* xd    = (const float*)d_in[1];
    const float* Wq    = (const float*)d_in[2];
    const float* bq    = (const float*)d_in[3];
    const float* Wk    = (const float*)d_in[4];
    const float* bk    = (const float*)d_in[5];
    const float* Wv    = (const float*)d_in[6];
    const float* bv    = (const float*)d_in[7];
    const float* gamma = (const float*)d_in[8];
    float* out = (float*)d_out;

    // ws (u16): qfT 512K | kfT 512K | vfT 4M | WfT 80K | ball
    u16* qfT  = (u16*)d_ws;
    u16* kfT  = qfT + (size_t)524288;
    u16* vfT  = kfT + (size_t)524288;
    u16* WfT  = vfT + (size_t)4194304;
    float* bl = (float*)(WfT + 81920);

    prep_w_kernel<<<322, 256, 0, stream>>>(Wq, bq, Wk, bk, Wv, bv, WfT, bl);
    proj_kernel<<<512, 256, 0, stream>>>(xc, xd, WfT, bl, qfT, kfT, vfT);
    flash_kernel<<<512, 512, 0, stream>>>(qfT, kfT, vfT, xc, gamma, out);
}

// Round 20
// 153.782 us; speedup vs baseline: 1.0718x; 1.0056x over previous
//
#include <hip/hip_runtime.h>

typedef unsigned short u16;
typedef unsigned int u32;
typedef short v8s __attribute__((ext_vector_type(8)));
typedef float v16f __attribute__((ext_vector_type(16)));
typedef unsigned int v2u __attribute__((ext_vector_type(2)));

#define MFMA(a, b, c) __builtin_amdgcn_mfma_f32_32x32x16_bf16(a, b, c, 0, 0, 0)
#define L2E 1.44269504088896f

union U8 { v8s s; uint4 u4; u32 u[4]; };

__device__ __forceinline__ u16 f2bf(float x) {            // round-nearest-even
    u32 u = __float_as_uint(x);
    return (u16)((u + 0x7FFFu + ((u >> 16) & 1u)) >> 16);
}
__device__ __forceinline__ u32 pk2(float a, float b) {
    return (u32)f2bf(a) | ((u32)f2bf(b) << 16);
}
// RTZ bf16x2 pack in ONE instruction
__device__ __forceinline__ u32 pkz(float e0, float e1) {
    return __builtin_amdgcn_perm(__float_as_uint(e1), __float_as_uint(e0), 0x07060302u);
}

// ======== frag-tiled layouts (u16 units), identical to R8-R10 ========
// qfT/kfT: [b][t32][f][lane][j]   t32 = (q|key)>>5   (4*128*2*512)
// vfT:     [b][ct][tk][lane][j]   ct = ch>>5, tk = key>>4 (4*8*256*512)
// WfT:     [cht][kc][lane][j]     cht = ch>>5 (10)       (160*512)

// ---- prep_w ----
__global__ __launch_bounds__(256) void prep_w_kernel(
    const float* __restrict__ Wq, const float* __restrict__ bq,
    const float* __restrict__ Wk, const float* __restrict__ bk,
    const float* __restrict__ Wv, const float* __restrict__ bv,
    u16* __restrict__ WfT, float* __restrict__ ball)
{
    int tid = blockIdx.x * 256 + threadIdx.x;
    if (tid < 81920) {
        int ch = tid >> 8, c = tid & 255;
        float w;
        if (ch < 32)      w = Wq[ch * 256 + c];
        else if (ch < 64) w = Wk[(ch - 32) * 256 + c] * L2E;
        else              w = Wv[(ch - 64) * 256 + c];
        int tile = (ch >> 5) * 16 + (c >> 4);
        int lane = ((c >> 3) & 1) * 32 + (ch & 31);
        WfT[tile * 512 + lane * 8 + (c & 7)] = f2bf(w);
    } else if (tid < 82240) {
        int i = tid - 81920;
        float bb;
        if (i < 32)      bb = bq[i];
        else if (i < 64) bb = bk[i - 32] * L2E;
        else             bb = bv[i - 64];
        ball[i] = bb;
    }
}

// ---- proj R19: stride 264->266 (read banks coprime permutation,         ----
// ---- conflict-minimal) + 5 waves x 2 jobs (perfect balance vs 2/2/3/3). ----
// ---- Grid 512 x 320 threads, 2 blocks/CU.                               ----
__global__ __launch_bounds__(320, 2) void proj_kernel(
    const float* __restrict__ xc, const float* __restrict__ xd,
    const u16* __restrict__ WfT, const float* __restrict__ ball,
    u16* __restrict__ qfT, u16* __restrict__ kfT, u16* __restrict__ vfT)
{
    __shared__ u16 xls[2][32][266];   // [arr][n][c] bf16, 34.0 KB; 133w%32=5 coprime
    int blk = blockIdx.x, b = blk >> 7, n0 = (blk & 127) * 32;
    int t = threadIdx.x, lane = t & 63, wv = t >> 6;   // wv 0..4
    int hl = lane >> 5, l31 = lane & 31;

#pragma unroll
    for (int p = 0; p < 4; p++) {
        int s = p * 320 + t;
        if (s < 1024) {
            int arr = s >> 9, c4 = (s >> 3) & 63, n4s = s & 7;
            const float* src = arr ? xd : xc;
            size_t g0 = ((size_t)(b * 256 + c4 * 4)) * 4096 + n0 + n4s * 4;
            float4 r0 = *(const float4*)&src[g0];
            float4 r1 = *(const float4*)&src[g0 + 4096];
            float4 r2 = *(const float4*)&src[g0 + 8192];
            float4 r3 = *(const float4*)&src[g0 + 12288];
            *(uint2*)&xls[arr][n4s * 4 + 0][c4 * 4] = make_uint2(pk2(r0.x, r1.x), pk2(r2.x, r3.x));
            *(uint2*)&xls[arr][n4s * 4 + 1][c4 * 4] = make_uint2(pk2(r0.y, r1.y), pk2(r2.y, r3.y));
            *(uint2*)&xls[arr][n4s * 4 + 2][c4 * 4] = make_uint2(pk2(r0.z, r1.z), pk2(r2.z, r3.z));
            *(uint2*)&xls[arr][n4s * 4 + 3][c4 * 4] = make_uint2(pk2(r0.w, r1.w), pk2(r2.w, r3.w));
        }
    }
    __syncthreads();

    int nt = blk & 127;
    int n = n0 + l31;
    int vl = ((n >> 3) & 1) * 32, tk = n >> 4, j8 = n & 7;

#pragma unroll
    for (int jj = 0; jj < 2; jj++) {
        int j = wv + jj * 5;              // wave wv does jobs {wv, wv+5}
        int arr = (j != 0);
        const u16* wb = WfT + (size_t)(j * 16) * 512 + lane * 8;
        v16f acc = {};
#pragma unroll
        for (int kc = 0; kc < 16; kc++) {
            U8 bx, a;
            bx.u4 = *(const uint4*)&xls[arr][l31][kc * 16 + hl * 8];
            a.u4  = *(const uint4*)(wb + (size_t)kc * 512);
            acc = MFMA(a.s, bx.s, acc);
        }
        if (j <= 1) {
            u16* dst = j ? kfT : qfT;
#pragma unroll
            for (int i = 0; i < 8; i++) {
                int r = 2 * i;
                int row = (r & 3) + 8 * (r >> 2) + 4 * hl;
                float b0 = ball[j * 32 + row], b1 = ball[j * 32 + row + 1];
                u32 st = pk2(acc[r] + b0, acc[r + 1] + b1);
                size_t off = (((size_t)(b * 128 + nt) * 2 + (row >> 4)) * 512)
                           + (((row >> 3) & 1) * 32 + l31) * 8 + (row & 7);
                *(u32*)&dst[off] = st;
            }
        } else {
            int vi = j - 2;
            u16* vdst = vfT + (((size_t)(b * 8 + vi) * 256 + tk) * 512) + vl * 8 + j8;
#pragma unroll
            for (int r = 0; r < 16; r++) {
                int row = (r & 3) + 8 * (r >> 2) + 4 * hl;
                vdst[row * 8] = f2bf(acc[r] + ball[64 + vi * 32 + row]);
            }
        }
    }
}

// ---- flash R18 (frozen control, 60.0us): own-tile-in-reg, single K buf ----
union ShU {
    u32   P[2][8][520];           // [buf][tile][h*256+lane*4+i], pad->+8 banks/tile, 33.3 KB
    float red[4][2][16][64];      // epilogue kq-reduce (aliases P) 32 KB
};

__global__ __launch_bounds__(512, 4) void flash_kernel(
    const u16* __restrict__ qfT, const u16* __restrict__ kfT,
    const u16* __restrict__ vfT, const float* __restrict__ xccd,
    const float* __restrict__ gptr, float* __restrict__ outp)
{
    __shared__ ShU sh;
    __shared__ float lred[8][32];

    const int t = threadIdx.x, lane = t & 63, wv = t >> 6;
    const int hl = lane >> 5, l31 = lane & 31;
    const int blk = blockIdx.x;
    const int b  = (blk & 7) >> 1;                      // XCD-pair pinning
    const int qt = ((blk >> 3) << 1) | (blk & 1);       // 0..127
    const int kq = wv >> 2, chq = wv & 3;
    const int n0 = qt * 32;

    U8 qf0, qf1;
    {
        const u16* qp = qfT + ((size_t)(b * 128 + qt) * 2) * 512 + lane * 8;
        qf0.u4 = *(const uint4*)qp;
        qf1.u4 = *(const uint4*)(qp + 512);
    }

    v16f acc[2] = {};
    float lrun = 0.f;
    U8 rB0, rB1;                    // own tile's P fragments, reg-resident

    // producer K: tile(s) = s*8 + wv ; per-superstep stride 8192 u16
    const u16* kp = kfT + ((size_t)(b * 128 + wv)) * 1024 + lane * 8;
    // consumer V: ct = chq*2 + ctl ; ctl stride = 256*512 = 131072 u16
    const u16* vp = vfT + ((size_t)(b * 8 + chq * 2) * 256) * 512 + lane * 8;

    U8 kb[2];                       // SINGLE K buffer (no double-buffer)
    kb[0].u4 = *(const uint4*)(kp);
    kb[1].u4 = *(const uint4*)(kp + 512);

    auto produce = [&](int buf) {
        v16f E = {};
        E = MFMA(kb[0].s, qf0.s, E);
        E = MFMA(kb[1].s, qf1.s, E);
        u32 pkv[8];
#pragma unroll
        for (int j = 0; j < 8; j++)
            pkv[j] = pkz(__builtin_amdgcn_exp2f(E[2 * j]),
                         __builtin_amdgcn_exp2f(E[2 * j + 1]));
        float sl = 0.f;   // l partial: sum of bf16-ROUNDED P (matches PV numerator)
#pragma unroll
        for (int j = 0; j < 8; j++) {
            sl += __uint_as_float(pkv[j] & 0xFFFF0000u);
            sl += __uint_as_float(pkv[j] << 16);
        }
        lrun += sl;
        U8 B0, B1;
        v2u r;
        r = __builtin_amdgcn_permlane32_swap(pkv[0], pkv[2], 0, 0); B0.u[0] = r[0]; B0.u[2] = r[1];
        r = __builtin_amdgcn_permlane32_swap(pkv[1], pkv[3], 0, 0); B0.u[1] = r[0]; B0.u[3] = r[1];
        r = __builtin_amdgcn_permlane32_swap(pkv[4], pkv[6], 0, 0); B1.u[0] = r[0]; B1.u[2] = r[1];
        r = __builtin_amdgcn_permlane32_swap(pkv[5], pkv[7], 0, 0); B1.u[1] = r[0]; B1.u[3] = r[1];
        *(uint4*)&sh.P[buf][wv][lane * 4]       = B0.u4;
        *(uint4*)&sh.P[buf][wv][256 + lane * 4] = B1.u4;
        rB0 = B0; rB1 = B1;         // keep own tile in regs for j=0 consumption
    };

    produce(0);               // P for superstep 0 (uses kb = K tile 0)
    kb[0].u4 = *(const uint4*)(kp + 8192);        // K tile for superstep 1
    kb[1].u4 = *(const uint4*)(kp + 8192 + 512);
    __syncthreads();

    const int tb = kq * 4;    // this wave's 4 tile slots; consumed in chq-rotated order
#pragma unroll 1
    for (int s = 0; s < 16; s++) {
        const int cb = s & 1, nb = cb ^ 1;
        // j=0 tile is OWN tile (tb + chq == wv): take from registers, no LDS read
        const int T0  = s * 8 + wv;
        U8 bA0, bA1, bB0, bB1;
        bA0 = rB0;
        bA1 = rB1;
        U8 vA[2][2], vB[2][2];
        {
            const u16* v0p = vp + (size_t)(2 * T0) * 512;
            vA[0][0].u4 = *(const uint4*)(v0p);
            vA[0][1].u4 = *(const uint4*)(v0p + 512);
            vA[1][0].u4 = *(const uint4*)(v0p + 131072);
            vA[1][1].u4 = *(const uint4*)(v0p + 131072 + 512);
        }
        // produce next superstep's P (consumes kb); then reload kb = K(s+2)
        if (s < 15) {
            produce(nb);
            if (s < 14) {
                kb[0].u4 = *(const uint4*)(kp + (size_t)(s + 2) * 8192);
                kb[1].u4 = *(const uint4*)(kp + (size_t)(s + 2) * 8192 + 512);
            }
        }
        // PV over 4 rotated tile slots, B/V double-buffered (j>=1 tiles from LDS)
#pragma unroll
        for (int j = 0; j < 4; j++) {
            if (j < 3) {
                const int tln = tb + ((chq + j + 1) & 3);
                const int Tn  = s * 8 + tln;
                bB0.u4 = *(const uint4*)&sh.P[cb][tln][lane * 4];
                bB1.u4 = *(const uint4*)&sh.P[cb][tln][256 + lane * 4];
                const u16* vnp = vp + (size_t)(2 * Tn) * 512;
                vB[0][0].u4 = *(const uint4*)(vnp);
                vB[0][1].u4 = *(const uint4*)(vnp + 512);
                vB[1][0].u4 = *(const uint4*)(vnp + 131072);
                vB[1][1].u4 = *(const uint4*)(vnp + 131072 + 512);
            }
            __builtin_amdgcn_s_setprio(1);
            acc[0] = MFMA(vA[0][0].s, bA0.s, acc[0]);
            acc[0] = MFMA(vA[0][1].s, bA1.s, acc[0]);
            acc[1] = MFMA(vA[1][0].s, bA0.s, acc[1]);
            acc[1] = MFMA(vA[1][1].s, bA1.s, acc[1]);
            __builtin_amdgcn_s_setprio(0);
            bA0 = bB0; bA1 = bB1;
            vA[0][0] = vB[0][0]; vA[0][1] = vB[0][1];
            vA[1][0] = vB[1][0]; vA[1][1] = vB[1][1];
        }
        __syncthreads();
    }

    // ---- epilogue: l finalize, kq-reduce, scale, residual ----
    {
        v2u rr = __builtin_amdgcn_permlane32_swap(__float_as_uint(lrun),
                                                  __float_as_uint(lrun), 0, 0);
        float ltot = __uint_as_float(rr[0]) + __uint_as_float(rr[1]);
        if (lane < 32) lred[wv][l31] = ltot;
    }
    if (kq == 1) {
#pragma unroll
        for (int ct = 0; ct < 2; ct++)
#pragma unroll
            for (int r = 0; r < 16; r++)
                sh.red[chq][ct][r][lane] = acc[ct][r];
    }
    __syncthreads();
    if (kq == 0) {
        float lsum = 0.f;
#pragma unroll
        for (int w = 0; w < 8; w++) lsum += lred[w][l31];
        const float g = gptr[0];
        const float sc = g / lsum;
#pragma unroll
        for (int ct = 0; ct < 2; ct++)
#pragma unroll
            for (int r = 0; r < 16; r++) {
                float v = acc[ct][r] + sh.red[chq][ct][r][lane];
                int ch = chq * 64 + ct * 32 + (r & 3) + 8 * (r >> 2) + 4 * hl;
                size_t ga = ((size_t)(b * 256 + ch)) * 4096 + n0 + l31;
                outp[ga] = v * sc + xccd[ga];
            }
    }
}

extern "C" void kernel_launch(void* const* d_in, const int* in_sizes, int n_in,
                              void* d_out, int out_size, void* d_ws, size_t ws_size,
                              hipStream_t stream)
{
    const float* xc    = (const float*)d_in[0];
    const float* xd    = (const float*)d_in[1];
    const float* Wq    = (const float*)d_in[2];
    const float* bq    = (const float*)d_in[3];
    const float* Wk    = (const float*)d_in[4];
    const float* bk    = (const float*)d_in[5];
    const float* Wv    = (const float*)d_in[6];
    const float* bv    = (const float*)d_in[7];
    const float* gamma = (const float*)d_in[8];
    float* out = (float*)d_out;

    // ws (u16): qfT 512K | kfT 512K | vfT 4M | WfT 80K | ball
    u16* qfT  = (u16*)d_ws;
    u16* kfT  = qfT + (size_t)524288;
    u16* vfT  = kfT + (size_t)524288;
    u16* WfT  = vfT + (size_t)4194304;
    float* bl = (float*)(WfT + 81920);

    prep_w_kernel<<<322, 256, 0, stream>>>(Wq, bq, Wk, bk, Wv, bv, WfT, bl);
    proj_kernel<<<512, 320, 0, stream>>>(xc, xd, WfT, bl, qfT, kfT, vfT);
    flash_kernel<<<512, 512, 0, stream>>>(qfT, kfT, vfT, xc, gamma, out);
}

// Round 21
// 153.581 us; speedup vs baseline: 1.0732x; 1.0013x over previous
//
#include <hip/hip_runtime.h>

typedef unsigned short u16;
typedef unsigned int u32;
typedef short v8s __attribute__((ext_vector_type(8)));
typedef float v16f __attribute__((ext_vector_type(16)));
typedef unsigned int v2u __attribute__((ext_vector_type(2)));

#define MFMA(a, b, c) __builtin_amdgcn_mfma_f32_32x32x16_bf16(a, b, c, 0, 0, 0)
#define L2E 1.44269504088896f

union U8 { v8s s; uint4 u4; u32 u[4]; };

__device__ __forceinline__ u16 f2bf(float x) {            // round-nearest-even
    u32 u = __float_as_uint(x);
    return (u16)((u + 0x7FFFu + ((u >> 16) & 1u)) >> 16);
}
__device__ __forceinline__ u32 pk2(float a, float b) {
    return (u32)f2bf(a) | ((u32)f2bf(b) << 16);
}
// RTZ bf16x2 pack in ONE instruction
__device__ __forceinline__ u32 pkz(float e0, float e1) {
    return __builtin_amdgcn_perm(__float_as_uint(e1), __float_as_uint(e0), 0x07060302u);
}

// ======== frag-tiled layouts (u16 units), identical to R8-R10 ========
// qfT/kfT: [b][t32][f][lane][j]   t32 = (q|key)>>5   (4*128*2*512)
// vfT:     [b][ct][tk][lane][j]   ct = ch>>5, tk = key>>4 (4*8*256*512)
// WfT:     [cht][kc][lane][j]     cht = ch>>5 (10)       (160*512)

// ---- prep_w ----
__global__ __launch_bounds__(256) void prep_w_kernel(
    const float* __restrict__ Wq, const float* __restrict__ bq,
    const float* __restrict__ Wk, const float* __restrict__ bk,
    const float* __restrict__ Wv, const float* __restrict__ bv,
    u16* __restrict__ WfT, float* __restrict__ ball)
{
    int tid = blockIdx.x * 256 + threadIdx.x;
    if (tid < 81920) {
        int ch = tid >> 8, c = tid & 255;
        float w;
        if (ch < 32)      w = Wq[ch * 256 + c];
        else if (ch < 64) w = Wk[(ch - 32) * 256 + c] * L2E;
        else              w = Wv[(ch - 64) * 256 + c];
        int tile = (ch >> 5) * 16 + (c >> 4);
        int lane = ((c >> 3) & 1) * 32 + (ch & 31);
        WfT[tile * 512 + lane * 8 + (c & 7)] = f2bf(w);
    } else if (tid < 82240) {
        int i = tid - 81920;
        float bb;
        if (i < 32)      bb = bq[i];
        else if (i < 64) bb = bk[i - 32] * L2E;
        else             bb = bv[i - 64];
        ball[i] = bb;
    }
}

// ---- proj R20: TLP split. Grid 1024 = 512 tile-pairs; pp0 block does    ----
// ---- jobs 0-4 (stages xc+xd), pp1 block does jobs 5-9 (stages xd only). ----
// ---- 1 job/wave (was 2), occupancy 10 -> 20 waves/CU. Pair blocks land  ----
// ---- on the SAME XCD (blk, blk+8) so duplicated xd reads hit L2.        ----
__global__ __launch_bounds__(320, 5) void proj_kernel(
    const float* __restrict__ xc, const float* __restrict__ xd,
    const u16* __restrict__ WfT, const float* __restrict__ ball,
    u16* __restrict__ qfT, u16* __restrict__ kfT, u16* __restrict__ vfT)
{
    __shared__ u16 xls[2][32][266];   // [arr][n][c] bf16, 34.0 KB; 133w%32=5 coprime
    int blk = blockIdx.x;
    int nb = ((blk >> 4) << 3) | (blk & 7);   // tile id 0..511 (same-XCD pairing)
    int pp = (blk >> 3) & 1;                  // 0: jobs 0-4 ; 1: jobs 5-9
    int b = nb >> 7, n0 = (nb & 127) * 32;
    int t = threadIdx.x, lane = t & 63, wv = t >> 6;   // wv 0..4
    int hl = lane >> 5, l31 = lane & 31;

    if (pp == 0) {                 // needs xc (arr 0) + xd (arr 1): items 0..1023
#pragma unroll
        for (int p = 0; p < 4; p++) {
            int s = p * 320 + t;
            if (s < 1024) {
                int arr = s >> 9, c4 = (s >> 3) & 63, n4s = s & 7;
                const float* src = arr ? xd : xc;
                size_t g0 = ((size_t)(b * 256 + c4 * 4)) * 4096 + n0 + n4s * 4;
                float4 r0 = *(const float4*)&src[g0];
                float4 r1 = *(const float4*)&src[g0 + 4096];
                float4 r2 = *(const float4*)&src[g0 + 8192];
                float4 r3 = *(const float4*)&src[g0 + 12288];
                *(uint2*)&xls[arr][n4s * 4 + 0][c4 * 4] = make_uint2(pk2(r0.x, r1.x), pk2(r2.x, r3.x));
                *(uint2*)&xls[arr][n4s * 4 + 1][c4 * 4] = make_uint2(pk2(r0.y, r1.y), pk2(r2.y, r3.y));
                *(uint2*)&xls[arr][n4s * 4 + 2][c4 * 4] = make_uint2(pk2(r0.z, r1.z), pk2(r2.z, r3.z));
                *(uint2*)&xls[arr][n4s * 4 + 3][c4 * 4] = make_uint2(pk2(r0.w, r1.w), pk2(r2.w, r3.w));
            }
        }
    } else {                       // needs only xd (arr 1): items 512..1023
#pragma unroll
        for (int p = 0; p < 2; p++) {
            int s = 512 + p * 320 + t;
            if (s < 1024) {
                int c4 = (s >> 3) & 63, n4s = s & 7;
                size_t g0 = ((size_t)(b * 256 + c4 * 4)) * 4096 + n0 + n4s * 4;
                float4 r0 = *(const float4*)&xd[g0];
                float4 r1 = *(const float4*)&xd[g0 + 4096];
                float4 r2 = *(const float4*)&xd[g0 + 8192];
                float4 r3 = *(const float4*)&xd[g0 + 12288];
                *(uint2*)&xls[1][n4s * 4 + 0][c4 * 4] = make_uint2(pk2(r0.x, r1.x), pk2(r2.x, r3.x));
                *(uint2*)&xls[1][n4s * 4 + 1][c4 * 4] = make_uint2(pk2(r0.y, r1.y), pk2(r2.y, r3.y));
                *(uint2*)&xls[1][n4s * 4 + 2][c4 * 4] = make_uint2(pk2(r0.z, r1.z), pk2(r2.z, r3.z));
                *(uint2*)&xls[1][n4s * 4 + 3][c4 * 4] = make_uint2(pk2(r0.w, r1.w), pk2(r2.w, r3.w));
            }
        }
    }
    __syncthreads();

    int nt = nb & 127;
    int n = n0 + l31;
    int vl = ((n >> 3) & 1) * 32, tk = n >> 4, j8 = n & 7;

    {
        int j = wv + pp * 5;              // exactly one job per wave
        int arr = (j != 0);
        const u16* wb = WfT + (size_t)(j * 16) * 512 + lane * 8;
        v16f acc = {};
#pragma unroll
        for (int kc = 0; kc < 16; kc++) {
            U8 bx, a;
            bx.u4 = *(const uint4*)&xls[arr][l31][kc * 16 + hl * 8];
            a.u4  = *(const uint4*)(wb + (size_t)kc * 512);
            acc = MFMA(a.s, bx.s, acc);
        }
        if (j <= 1) {
            u16* dst = j ? kfT : qfT;
#pragma unroll
            for (int i = 0; i < 8; i++) {
                int r = 2 * i;
                int row = (r & 3) + 8 * (r >> 2) + 4 * hl;
                float b0 = ball[j * 32 + row], b1 = ball[j * 32 + row + 1];
                u32 st = pk2(acc[r] + b0, acc[r + 1] + b1);
                size_t off = (((size_t)(b * 128 + nt) * 2 + (row >> 4)) * 512)
                           + (((row >> 3) & 1) * 32 + l31) * 8 + (row & 7);
                *(u32*)&dst[off] = st;
            }
        } else {
            int vi = j - 2;
            u16* vdst = vfT + (((size_t)(b * 8 + vi) * 256 + tk) * 512) + vl * 8 + j8;
#pragma unroll
            for (int r = 0; r < 16; r++) {
                int row = (r & 3) + 8 * (r >> 2) + 4 * hl;
                vdst[row * 8] = f2bf(acc[r] + ball[64 + vi * 32 + row]);
            }
        }
    }
}

// ---- flash R18 (frozen control, ~58.8us): own-tile-in-reg, single K buf ----
union ShU {
    u32   P[2][8][520];           // [buf][tile][h*256+lane*4+i], pad->+8 banks/tile, 33.3 KB
    float red[4][2][16][64];      // epilogue kq-reduce (aliases P) 32 KB
};

__global__ __launch_bounds__(512, 4) void flash_kernel(
    const u16* __restrict__ qfT, const u16* __restrict__ kfT,
    const u16* __restrict__ vfT, const float* __restrict__ xccd,
    const float* __restrict__ gptr, float* __restrict__ outp)
{
    __shared__ ShU sh;
    __shared__ float lred[8][32];

    const int t = threadIdx.x, lane = t & 63, wv = t >> 6;
    const int hl = lane >> 5, l31 = lane & 31;
    const int blk = blockIdx.x;
    const int b  = (blk & 7) >> 1;                      // XCD-pair pinning
    const int qt = ((blk >> 3) << 1) | (blk & 1);       // 0..127
    const int kq = wv >> 2, chq = wv & 3;
    const int n0 = qt * 32;

    U8 qf0, qf1;
    {
        const u16* qp = qfT + ((size_t)(b * 128 + qt) * 2) * 512 + lane * 8;
        qf0.u4 = *(const uint4*)qp;
        qf1.u4 = *(const uint4*)(qp + 512);
    }

    v16f acc[2] = {};
    float lrun = 0.f;
    U8 rB0, rB1;                    // own tile's P fragments, reg-resident

    // producer K: tile(s) = s*8 + wv ; per-superstep stride 8192 u16
    const u16* kp = kfT + ((size_t)(b * 128 + wv)) * 1024 + lane * 8;
    // consumer V: ct = chq*2 + ctl ; ctl stride = 256*512 = 131072 u16
    const u16* vp = vfT + ((size_t)(b * 8 + chq * 2) * 256) * 512 + lane * 8;

    U8 kb[2];                       // SINGLE K buffer (no double-buffer)
    kb[0].u4 = *(const uint4*)(kp);
    kb[1].u4 = *(const uint4*)(kp + 512);

    auto produce = [&](int buf) {
        v16f E = {};
        E = MFMA(kb[0].s, qf0.s, E);
        E = MFMA(kb[1].s, qf1.s, E);
        u32 pkv[8];
#pragma unroll
        for (int j = 0; j < 8; j++)
            pkv[j] = pkz(__builtin_amdgcn_exp2f(E[2 * j]),
                         __builtin_amdgcn_exp2f(E[2 * j + 1]));
        float sl = 0.f;   // l partial: sum of bf16-ROUNDED P (matches PV numerator)
#pragma unroll
        for (int j = 0; j < 8; j++) {
            sl += __uint_as_float(pkv[j] & 0xFFFF0000u);
            sl += __uint_as_float(pkv[j] << 16);
        }
        lrun += sl;
        U8 B0, B1;
        v2u r;
        r = __builtin_amdgcn_permlane32_swap(pkv[0], pkv[2], 0, 0); B0.u[0] = r[0]; B0.u[2] = r[1];
        r = __builtin_amdgcn_permlane32_swap(pkv[1], pkv[3], 0, 0); B0.u[1] = r[0]; B0.u[3] = r[1];
        r = __builtin_amdgcn_permlane32_swap(pkv[4], pkv[6], 0, 0); B1.u[0] = r[0]; B1.u[2] = r[1];
        r = __builtin_amdgcn_permlane32_swap(pkv[5], pkv[7], 0, 0); B1.u[1] = r[0]; B1.u[3] = r[1];
        *(uint4*)&sh.P[buf][wv][lane * 4]       = B0.u4;
        *(uint4*)&sh.P[buf][wv][256 + lane * 4] = B1.u4;
        rB0 = B0; rB1 = B1;         // keep own tile in regs for j=0 consumption
    };

    produce(0);               // P for superstep 0 (uses kb = K tile 0)
    kb[0].u4 = *(const uint4*)(kp + 8192);        // K tile for superstep 1
    kb[1].u4 = *(const uint4*)(kp + 8192 + 512);
    __syncthreads();

    const int tb = kq * 4;    // this wave's 4 tile slots; consumed in chq-rotated order
#pragma unroll 1
    for (int s = 0; s < 16; s++) {
        const int cb = s & 1, nb = cb ^ 1;
        // j=0 tile is OWN tile (tb + chq == wv): take from registers, no LDS read
        const int T0  = s * 8 + wv;
        U8 bA0, bA1, bB0, bB1;
        bA0 = rB0;
        bA1 = rB1;
        U8 vA[2][2], vB[2][2];
        {
            const u16* v0p = vp + (size_t)(2 * T0) * 512;
            vA[0][0].u4 = *(const uint4*)(v0p);
            vA[0][1].u4 = *(const uint4*)(v0p + 512);
            vA[1][0].u4 = *(const uint4*)(v0p + 131072);
            vA[1][1].u4 = *(const uint4*)(v0p + 131072 + 512);
        }
        // produce next superstep's P (consumes kb); then reload kb = K(s+2)
        if (s < 15) {
            produce(nb);
            if (s < 14) {
                kb[0].u4 = *(const uint4*)(kp + (size_t)(s + 2) * 8192);
                kb[1].u4 = *(const uint4*)(kp + (size_t)(s + 2) * 8192 + 512);
            }
        }
        // PV over 4 rotated tile slots, B/V double-buffered (j>=1 tiles from LDS)
#pragma unroll
        for (int j = 0; j < 4; j++) {
            if (j < 3) {
                const int tln = tb + ((chq + j + 1) & 3);
                const int Tn  = s * 8 + tln;
                bB0.u4 = *(const uint4*)&sh.P[cb][tln][lane * 4];
                bB1.u4 = *(const uint4*)&sh.P[cb][tln][256 + lane * 4];
                const u16* vnp = vp + (size_t)(2 * Tn) * 512;
                vB[0][0].u4 = *(const uint4*)(vnp);
                vB[0][1].u4 = *(const uint4*)(vnp + 512);
                vB[1][0].u4 = *(const uint4*)(vnp + 131072);
                vB[1][1].u4 = *(const uint4*)(vnp + 131072 + 512);
            }
            __builtin_amdgcn_s_setprio(1);
            acc[0] = MFMA(vA[0][0].s, bA0.s, acc[0]);
            acc[0] = MFMA(vA[0][1].s, bA1.s, acc[0]);
            acc[1] = MFMA(vA[1][0].s, bA0.s, acc[1]);
            acc[1] = MFMA(vA[1][1].s, bA1.s, acc[1]);
            __builtin_amdgcn_s_setprio(0);
            bA0 = bB0; bA1 = bB1;
            vA[0][0] = vB[0][0]; vA[0][1] = vB[0][1];
            vA[1][0] = vB[1][0]; vA[1][1] = vB[1][1];
        }
        __syncthreads();
    }

    // ---- epilogue: l finalize, kq-reduce, scale, residual ----
    {
        v2u rr = __builtin_amdgcn_permlane32_swap(__float_as_uint(lrun),
                                                  __float_as_uint(lrun), 0, 0);
        float ltot = __uint_as_float(rr[0]) + __uint_as_float(rr[1]);
        if (lane < 32) lred[wv][l31] = ltot;
    }
    if (kq == 1) {
#pragma unroll
        for (int ct = 0; ct < 2; ct++)
#pragma unroll
            for (int r = 0; r < 16; r++)
                sh.red[chq][ct][r][lane] = acc[ct][r];
    }
    __syncthreads();
    if (kq == 0) {
        float lsum = 0.f;
#pragma unroll
        for (int w = 0; w < 8; w++) lsum += lred[w][l31];
        const float g = gptr[0];
        const float sc = g / lsum;
#pragma unroll
        for (int ct = 0; ct < 2; ct++)
#pragma unroll
            for (int r = 0; r < 16; r++) {
                float v = acc[ct][r] + sh.red[chq][ct][r][lane];
                int ch = chq * 64 + ct * 32 + (r & 3) + 8 * (r >> 2) + 4 * hl;
                size_t ga = ((size_t)(b * 256 + ch)) * 4096 + n0 + l31;
                outp[ga] = v * sc + xccd[ga];
            }
    }
}

extern "C" void kernel_launch(void* const* d_in, const int* in_sizes, int n_in,
                              void* d_out, int out_size, void* d_ws, size_t ws_size,
                              hipStream_t stream)
{
    const float* xc    = (const float*)d_in[0];
    const float* xd    = (const float*)d_in[1];
    const float* Wq    = (const float*)d_in[2];
    const float* bq    = (const float*)d_in[3];
    const float* Wk    = (const float*)d_in[4];
    const float* bk    = (const float*)d_in[5];
    const float* Wv    = (const float*)d_in[6];
    const float* bv    = (const float*)d_in[7];
    const float* gamma = (const float*)d_in[8];
    float* out = (float*)d_out;

    // ws (u16): qfT 512K | kfT 512K | vfT 4M | WfT 80K | ball
    u16* qfT  = (u16*)d_ws;
    u16* kfT  = qfT + (size_t)524288;
    u16* vfT  = kfT + (size_t)524288;
    u16* WfT  = vfT + (size_t)4194304;
    float* bl = (float*)(WfT + 81920);

    prep_w_kernel<<<322, 256, 0, stream>>>(Wq, bq, Wk, bk, Wv, bv, WfT, bl);
    proj_kernel<<<1024, 320, 0, stream>>>(xc, xd, WfT, bl, qfT, kfT, vfT);
    flash_kernel<<<512, 512, 0, stream>>>(qfT, kfT, vfT, xc, gamma, out);
}